// Round 5
// baseline (451.616 us; speedup 1.0000x reference)
//
#include <hip/hip_runtime.h>
#include <math.h>

#define BATCH 8
#define NPT   2048
#define DIM   32
#define RPB   64                      // rows per block: 4 strips of 16
#define STRIPS (RPB / 16)
#define NBLKR (NPT / RPB)             // 32 row blocks
#define CPW   (NPT / 4)               // 512 cols per wave
#define NT    (CPW / 16)              // 32 col-tiles of 16 per wave
#define L2E   1.44269504088896f
#define LN2   0.6931471805599453f
#define BN    (BATCH * NPT)

typedef __attribute__((ext_vector_type(8))) _Float16 half8;
typedef __attribute__((ext_vector_type(4))) float floatx4;
typedef unsigned short u16;
typedef unsigned int u32;

__device__ __forceinline__ u16 f2h_bits(float v) {
    _Float16 h = (_Float16)v;
    return *(u16*)&h;
}
__device__ __forceinline__ float exp2v(float x) { return __builtin_amdgcn_exp2f(x); }

struct SymSet {
    const u16* Ah;        // row-side plain fp16 [BATCH][NPT][DIM]
    const u16* Bh;        // col-side log2e-scaled fp16
    const float* tls;     // log2e*(pot+cw) on cols
    const float* qX;      // 0.5*||row||^2
    const float* bmIn;    // [BATCH][128] per-16 max of (pot+cw) on cols
    const float* cwNext;
    const float* prev;
    float* out;
    float* tlsOut;
    float* bmOut;
};
struct FusedSet {
    const u16* Xh;        // rows X plain fp16
    const u16* Ysh;       // cols Y log2e-scaled fp16
    const float* tlsF;    // log2e*(f+c_x) per row  (g-side row bias)
    const float* qX;
    const float* bmF;     // -> TmaxF (row bias normalization)
    const float* c_x;
    const float* prevF;   // f state (averaging)
    float* outF;
    float* tlsFOut;
    float* bmFOut;
    // g-side state recomputed per block from last launch's partials:
    const float* gpIn;    // [BATCH][NBLKR][NPT] from previous launch
    float* gpOut;         // this launch's partials (other buffer)
    const float* gbIn;    // g_{it-1}
    float* gbOut;         // g_it (written by xb==0 block only)
    const float* stfIn;   // scalar TmaxF used when gpIn was produced
    float* stfOut;        // scalar TmaxF used for gpOut (this launch)
    const float* qY;
    const float* c_y;
    int first;            // it==0: g=0, skip gpIn merge
};
struct CtArgs { FusedSet fs; SymSet s[2]; int average; };

// blockIdx.y==0 (fused): PROLOGUE recomputes this iteration's g from last
// launch's column partials (gfin folded in; 256KB L2 read per block),
// stores pre-subtracted col weights L2E*(tc-TmaxG) in LDS, then the main
// pass computes f-row LSE over kxy AND this launch's g-col partials.
//   acc = L2E*x.y + (tf_l - L2E*TmaxF)   (row bias in MFMA C-operand)
//   e' = 2^acc; gl += e';  sumF += 2^sg[col] * e'
// blockIdx.y==1,2: symmetric sets, col bias folded into MFMA C-operand.
// All cross-iteration deps are cross-LAUNCH; within a launch reads/writes
// touch opposite ping-pong buffers (race-free by construction).
__global__ __launch_bounds__(256, 3) void ct3_kernel(CtArgs args) {
    const int batch = blockIdx.z;
    const int xb = blockIdx.x;
    const int row0 = xb * RPB;
    const int tid  = threadIdx.x;
    const int w = tid >> 6, lane = tid & 63, n = lane & 15, quad = lane >> 4;
    const int qk = quad * 8;
    const size_t pbase = (size_t)batch * NPT * DIM;
    const size_t vbase = (size_t)batch * NPT;

    __shared__ float lsum[RPB][4];
    __shared__ float sg[NPT];         // fused: L2E*(g+c_y - TmaxG) per col

    if (blockIdx.y == 0) {
        // ---------------- fused cross pass ----------------
        const FusedSet fs = args.fs;
        const u16* __restrict__ Ah = fs.Xh + pbase;
        const u16* __restrict__ Bh = fs.Ysh + pbase;
        const float* __restrict__ tf = fs.tlsF + vbase;
        const float* __restrict__ qYp = fs.qY + vbase;
        const float* __restrict__ cyp = fs.c_y + vbase;
        const float* __restrict__ gbInp = fs.gbIn + vbase;
        float* gbOutp = fs.gbOut + vbase;

        // ---- prologue: rebuild g_it and col-weight table in LDS ----
        float tcv[8];
        float lmax = -1e30f;
        if (!fs.first) {
            const float mfPrev = fs.stfIn[0];
            const float* gpi = fs.gpIn + (size_t)batch * NBLKR * NPT;
            #pragma unroll
            for (int j = 0; j < 8; j++) {
                const int col = tid + j * 256;
                float G = 0.f;
                #pragma unroll 8
                for (int p = 0; p < NBLKR; p++) G += gpi[(size_t)p * NPT + col];
                float raw = qYp[col] - (mfPrev + __logf(G));
                float gnew = 0.5f * (gbInp[col] + raw);
                if (xb == 0) gbOutp[col] = gnew;
                float tc = gnew + cyp[col];
                tcv[j] = tc;
                lmax = fmaxf(lmax, tc);
            }
        } else {
            #pragma unroll
            for (int j = 0; j < 8; j++) {
                const int col = tid + j * 256;
                if (xb == 0) gbOutp[col] = 0.f;
                float tc = cyp[col];
                tcv[j] = tc;
                lmax = fmaxf(lmax, tc);
            }
        }
        #pragma unroll
        for (int m = 1; m < 64; m <<= 1) lmax = fmaxf(lmax, __shfl_xor(lmax, m, 64));
        if (lane == 0) lsum[0][w] = lmax;
        __syncthreads();
        const float TmaxG = fmaxf(fmaxf(lsum[0][0], lsum[0][1]),
                                  fmaxf(lsum[0][2], lsum[0][3]));
        #pragma unroll
        for (int j = 0; j < 8; j++)
            sg[tid + j * 256] = L2E * (tcv[j] - TmaxG);
        __syncthreads();

        // ---- row-side setup ----
        half8 ah[STRIPS];
        #pragma unroll
        for (int s = 0; s < STRIPS; s++) {
            size_t off = (size_t)(row0 + s * 16 + n) * DIM + qk;
            ah[s] = *(const half8*)(Ah + off);
        }
        float mf = fmaxf(fs.bmF[batch * 128 + lane], fs.bmF[batch * 128 + 64 + lane]);
        #pragma unroll
        for (int m = 1; m < 64; m <<= 1) mf = fmaxf(mf, __shfl_xor(mf, m, 64));
        const float l2eTF = L2E * mf;
        if (xb == 0 && tid == 0) fs.stfOut[0] = mf;

        floatx4 cis[STRIPS];
        #pragma unroll
        for (int s = 0; s < STRIPS; s++)
            #pragma unroll
            for (int r = 0; r < 4; r++)
                cis[s][r] = tf[row0 + s * 16 + quad * 4 + r] - l2eTF;

        float sumF[STRIPS][4];
        #pragma unroll
        for (int s = 0; s < STRIPS; s++)
            #pragma unroll
            for (int r = 0; r < 4; r++) sumF[s][r] = 0.0f;

        const int c0 = w * CPW + n;
        const u16* bp = Bh + (size_t)c0 * DIM + qk;
        float* gpc = fs.gpOut + ((size_t)batch * NBLKR + xb) * NPT + c0;

        half8 bb[4];
        bb[0] = *(const half8*)bp;
        bb[1] = *(const half8*)(bp + (size_t)16 * DIM);

        auto tile = [&](half8 b, int idx) {
            float wq = exp2v(sg[c0 + idx * 16]);
            floatx4 acc[STRIPS];
            #pragma unroll
            for (int s = 0; s < STRIPS; s++)
                acc[s] = __builtin_amdgcn_mfma_f32_16x16x32_f16(ah[s], b, cis[s], 0, 0, 0);
            float gl = 0.0f;
            #pragma unroll
            for (int s = 0; s < STRIPS; s++)
                #pragma unroll
                for (int r = 0; r < 4; r++) {
                    float e = exp2v(acc[s][r]);
                    sumF[s][r] = fmaf(wq, e, sumF[s][r]);
                    gl += e;
                }
            gl += __shfl_xor(gl, 16, 64);
            gl += __shfl_xor(gl, 32, 64);
            if (lane < 16) gpc[idx * 16] = gl;
        };

        #pragma unroll 1
        for (int ch = 0; ch < NT; ch += 4) {
            #pragma unroll
            for (int j = 0; j < 4; j++) {
                int nx = ch + j + 2;
                int nxc = nx < NT ? nx : NT - 1;          // clamped, branch-free
                bb[(j + 2) & 3] = *(const half8*)(bp + (size_t)nxc * 16 * DIM);
                tile(bb[j], ch + j);
            }
        }

        #pragma unroll
        for (int s = 0; s < STRIPS; s++)
            #pragma unroll
            for (int r = 0; r < 4; r++) {
                float v = sumF[s][r];
                #pragma unroll
                for (int m = 1; m < 16; m <<= 1) v += __shfl_xor(v, m, 64);
                if (n == 0) lsum[s * 16 + quad * 4 + r][w] = v;
            }
        __syncthreads();

        if (tid < RPB) {
            float T = (lsum[tid][0] + lsum[tid][1]) + (lsum[tid][2] + lsum[tid][3]);
            int l = row0 + tid;
            float lse = TmaxG + __logf(T) - LN2 * (tf[l] - l2eTF);
            float val = fs.qX[vbase + l] - lse;
            if (args.average) val = 0.5f * (fs.prevF[vbase + l] + val);
            fs.outF[vbase + l] = val;
            float tc = val + fs.c_x[vbase + l];
            fs.tlsFOut[vbase + l] = L2E * tc;
            float bm = tc;
            #pragma unroll
            for (int m = 1; m < 16; m <<= 1) bm = fmaxf(bm, __shfl_xor(bm, m, 64));
            if ((tid & 15) == 0)
                fs.bmFOut[batch * 128 + xb * STRIPS + (tid >> 4)] = bm;
        }
    } else {
        // ---------------- symmetric sets (unchanged from 325us kernel) ----
        const SymSet cs = args.s[blockIdx.y - 1];
        const u16* __restrict__ Ah = cs.Ah + pbase;
        const u16* __restrict__ Bh = cs.Bh + pbase;
        const float* __restrict__ tls = cs.tls + vbase;

        half8 ah[STRIPS];
        #pragma unroll
        for (int s = 0; s < STRIPS; s++) {
            size_t off = (size_t)(row0 + s * 16 + n) * DIM + qk;
            ah[s] = *(const half8*)(Ah + off);
        }

        float tmv = fmaxf(cs.bmIn[batch * 128 + lane], cs.bmIn[batch * 128 + 64 + lane]);
        #pragma unroll
        for (int m = 1; m < 64; m <<= 1) tmv = fmaxf(tmv, __shfl_xor(tmv, m, 64));
        const float Tmax = tmv;
        const float l2eTmax = L2E * Tmax;

        float sum[STRIPS][4];
        #pragma unroll
        for (int s = 0; s < STRIPS; s++)
            #pragma unroll
            for (int r = 0; r < 4; r++) sum[s][r] = 0.0f;

        const int c0 = w * CPW + n;
        const u16* bp = Bh + (size_t)c0 * DIM + qk;
        const float* tp = tls + c0;

        half8 bb[4];
        float tt[4];
        bb[0] = *(const half8*)bp;                       tt[0] = tp[0];
        bb[1] = *(const half8*)(bp + (size_t)16 * DIM);  tt[1] = tp[16];

        auto tile = [&](half8 b, float t) {
            float bias = t - l2eTmax;
            floatx4 ci = (floatx4){bias, bias, bias, bias};
            floatx4 acc[STRIPS];
            #pragma unroll
            for (int s = 0; s < STRIPS; s++)
                acc[s] = __builtin_amdgcn_mfma_f32_16x16x32_f16(ah[s], b, ci, 0, 0, 0);
            #pragma unroll
            for (int s = 0; s < STRIPS; s++)
                #pragma unroll
                for (int r = 0; r < 4; r++)
                    sum[s][r] += exp2v(acc[s][r]);
        };

        #pragma unroll 1
        for (int ch = 0; ch < NT; ch += 4) {
            #pragma unroll
            for (int j = 0; j < 4; j++) {
                int nx = ch + j + 2;
                int nxc = nx < NT ? nx : NT - 1;
                bb[(j + 2) & 3] = *(const half8*)(bp + (size_t)nxc * 16 * DIM);
                tt[(j + 2) & 3] = tp[nxc * 16];
                tile(bb[j], tt[j]);
            }
        }

        #pragma unroll
        for (int s = 0; s < STRIPS; s++)
            #pragma unroll
            for (int r = 0; r < 4; r++) {
                float v = sum[s][r];
                #pragma unroll
                for (int m = 1; m < 16; m <<= 1) v += __shfl_xor(v, m, 64);
                if (n == 0) lsum[s * 16 + quad * 4 + r][w] = v;
            }
        __syncthreads();

        if (tid < RPB) {
            float T = (lsum[tid][0] + lsum[tid][1]) + (lsum[tid][2] + lsum[tid][3]);
            int l = row0 + tid;
            float lse = Tmax + __logf(T);
            float val = cs.qX[vbase + l] - lse;
            if (args.average) val = 0.5f * (cs.prev[vbase + l] + val);
            cs.out[vbase + l] = val;
            float tc = val + cs.cwNext[vbase + l];
            cs.tlsOut[vbase + l] = L2E * tc;
            float bm = tc;
            #pragma unroll
            for (int m = 1; m < 16; m <<= 1) bm = fmaxf(bm, __shfl_xor(bm, m, 64));
            if ((tid & 15) == 0)
                cs.bmOut[batch * 128 + xb * STRIPS + (tid >> 4)] = bm;
        }
    }
}

struct FrArgs {
    const float* gpart;   // gp[1]: partials from final (unaveraged) pass
    const float* stf;     // scalar TmaxF for that pass
    const float* qY;
    const float* a;
    const float* b;
    const float* ctA;
    const float* ctX;
    const float* ctY;
    float* out;           // atomicAdd target (zeroed by init each replay)
};

// Final gfin + divergence reduction fused: 256 blocks (8 batch x 32 chunks
// of 64 cols). Computes ctB on the fly, accumulates a*(ctA-ctX)+b*(ctB-ctY).
__global__ __launch_bounds__(256) void finredux_kernel(FrArgs fa) {
    const int tid = threadIdx.x;
    const int batch = blockIdx.x >> 5;
    const int chunk = blockIdx.x & 31;
    const int g = tid >> 6, c = tid & 63;
    const int col = chunk * 64 + c;

    __shared__ float ps[4][64];
    const float mf = fa.stf[0];

    const float* gp = fa.gpart + ((size_t)batch * NBLKR + g) * NPT + col;
    float G = 0.0f;
    #pragma unroll
    for (int p = 0; p < NBLKR / 4; p++) G += gp[(size_t)p * 4 * NPT];
    ps[g][c] = G;
    __syncthreads();

    if (tid < 64) {
        float Gt = (ps[0][tid] + ps[1][tid]) + (ps[2][tid] + ps[3][tid]);
        const int colT = chunk * 64 + tid;
        const size_t idx = (size_t)batch * NPT + colT;
        float ctB = fa.qY[idx] - (mf + __logf(Gt));
        float acc = fa.a[idx] * (fa.ctA[idx] - fa.ctX[idx])
                  + fa.b[idx] * (ctB - fa.ctY[idx]);
        #pragma unroll
        for (int off = 32; off > 0; off >>= 1) acc += __shfl_down(acc, off, 64);
        if (tid == 0) atomicAdd(fa.out, acc * (1.0f / (float)BATCH));
    }
}

struct InitArgs {
    const float *x, *a, *y, *b;
    float *c_x, *c_y, *qx, *qy;
    u16 *xh, *yh, *xsh, *ysh;
    float *f0, *fx0, *fy0;
    float *tlsF0, *tlsFx0, *tlsFy0;
    float *bmF0, *bmFx0, *bmFy0;
    float *out;
};

__global__ __launch_bounds__(256) void init_kernel(InitArgs ia) {
    int idx = blockIdx.x * 256 + threadIdx.x;
    if (idx >= BN) return;
    if (idx == 0) ia.out[0] = 0.f;    // finredux atomicAdd target, per replay
    const float* xp = ia.x + (size_t)idx * DIM;
    const float* yp = ia.y + (size_t)idx * DIM;
    u32* xhp  = (u32*)ia.xh  + (size_t)idx * (DIM / 2);
    u32* yhp  = (u32*)ia.yh  + (size_t)idx * (DIM / 2);
    u32* xshp = (u32*)ia.xsh + (size_t)idx * (DIM / 2);
    u32* yshp = (u32*)ia.ysh + (size_t)idx * (DIM / 2);
    float sx = 0.f, sy = 0.f;
    #pragma unroll
    for (int d = 0; d < DIM; d += 2) {
        float v0 = xp[d], v1 = xp[d + 1];
        sx += v0 * v0 + v1 * v1;
        xhp[d / 2]  = (u32)f2h_bits(v0) | ((u32)f2h_bits(v1) << 16);
        xshp[d / 2] = (u32)f2h_bits(L2E * v0) | ((u32)f2h_bits(L2E * v1) << 16);
        float u0 = yp[d], u1 = yp[d + 1];
        sy += u0 * u0 + u1 * u1;
        yhp[d / 2]  = (u32)f2h_bits(u0) | ((u32)f2h_bits(u1) << 16);
        yshp[d / 2] = (u32)f2h_bits(L2E * u0) | ((u32)f2h_bits(L2E * u1) << 16);
    }
    float qxv = 0.5f * sx, qyv = 0.5f * sy;
    ia.qx[idx] = qxv; ia.qy[idx] = qyv;
    float cxv = __logf(ia.a[idx]) - qxv;
    float cyv = __logf(ia.b[idx]) - qyv;
    ia.c_x[idx] = cxv; ia.c_y[idx] = cyv;
    ia.f0[idx] = 0.f; ia.fx0[idx] = 0.f; ia.fy0[idx] = 0.f;
    ia.tlsF0[idx] = L2E * cxv;
    ia.tlsFx0[idx] = L2E * cxv; ia.tlsFy0[idx] = L2E * cyv;
    float mx = cxv, my = cyv;
    #pragma unroll
    for (int m = 1; m < 16; m <<= 1) {
        mx = fmaxf(mx, __shfl_xor(mx, m, 32));
        my = fmaxf(my, __shfl_xor(my, m, 32));
    }
    if ((threadIdx.x & 15) == 0) {
        int g = idx >> 4;
        ia.bmF0[g] = mx; ia.bmFx0[g] = mx;
        ia.bmFy0[g] = my;
    }
}

extern "C" void kernel_launch(void* const* d_in, const int* in_sizes, int n_in,
                              void* d_out, int out_size, void* d_ws, size_t ws_size,
                              hipStream_t stream) {
    const float* x = (const float*)d_in[0];
    const float* a = (const float*)d_in[1];
    const float* y = (const float*)d_in[2];
    const float* b = (const float*)d_in[3];
    float* out = (float*)d_out;

    float* ws = (float*)d_ws;
    float* c_x = ws + 0 * BN;
    float* c_y = ws + 1 * BN;
    float* qx  = ws + 2 * BN;
    float* qy  = ws + 3 * BN;
    float* fb[2]  = { ws + 4 * BN,  ws + 5 * BN };
    float* gbb[2] = { ws + 6 * BN,  ws + 7 * BN };
    float* fxb[2] = { ws + 8 * BN,  ws + 9 * BN };
    float* fyb[2] = { ws + 10 * BN, ws + 11 * BN };
    float* ctA = ws + 12 * BN;
    float* ctX = ws + 14 * BN;
    float* ctY = ws + 15 * BN;
    float* tlsF[2]  = { ws + 16 * BN, ws + 17 * BN };
    float* tlsFx[2] = { ws + 20 * BN, ws + 21 * BN };
    float* tlsFy[2] = { ws + 22 * BN, ws + 23 * BN };
    float* dummyT = ws + 24 * BN;
    float* small = ws + 25 * BN;
    float* bmF[2]  = { small + 0 * 1024, small + 1 * 1024 };
    float* bmFx[2] = { small + 4 * 1024, small + 5 * 1024 };
    float* bmFy[2] = { small + 6 * 1024, small + 7 * 1024 };
    float* dummyB = small + 8 * 1024;
    float* stf = small + 9 * 1024;          // float[2] scalar TmaxF slots
    u16* bf = (u16*)(small + 10 * 1024);
    const size_t AS = (size_t)BN * DIM;
    u16* xh  = bf + 0 * AS;
    u16* yh  = bf + 1 * AS;
    u16* xsh = bf + 2 * AS;
    u16* ysh = bf + 3 * AS;
    float* gp[2];
    gp[0] = (float*)(bf + 4 * AS);          // [BATCH][NBLKR][NPT] = 2 MB
    gp[1] = gp[0] + (size_t)BATCH * NBLKR * NPT;

    InitArgs ia;
    ia.x = x; ia.a = a; ia.y = y; ia.b = b;
    ia.c_x = c_x; ia.c_y = c_y; ia.qx = qx; ia.qy = qy;
    ia.xh = xh; ia.yh = yh; ia.xsh = xsh; ia.ysh = ysh;
    ia.f0 = fb[0]; ia.fx0 = fxb[0]; ia.fy0 = fyb[0];
    ia.tlsF0 = tlsF[0]; ia.tlsFx0 = tlsFx[0]; ia.tlsFy0 = tlsFy[0];
    ia.bmF0 = bmF[0]; ia.bmFx0 = bmFx[0]; ia.bmFy0 = bmFy[0];
    ia.out = out;
    init_kernel<<<BN / 256, 256, 0, stream>>>(ia);

    dim3 grid(NBLKR, 3, BATCH);
    for (int it = 0; it <= 10; it++) {
        const int cur = it & 1;
        const int avg = (it < 10);
        CtArgs ar;
        ar.average = avg;
        // fused: f-update over kxy + g-partials; g recomputed in prologue
        ar.fs.Xh = xh; ar.fs.Ysh = ysh;
        ar.fs.tlsF = tlsF[cur]; ar.fs.qX = qx; ar.fs.bmF = bmF[cur];
        ar.fs.c_x = c_x; ar.fs.prevF = fb[cur];
        ar.fs.outF   = avg ? fb[cur ^ 1]   : ctA;
        ar.fs.tlsFOut = avg ? tlsF[cur ^ 1] : dummyT;
        ar.fs.bmFOut  = avg ? bmF[cur ^ 1]  : dummyB;
        ar.fs.gpIn = gp[cur]; ar.fs.gpOut = gp[cur ^ 1];
        ar.fs.gbIn = gbb[cur]; ar.fs.gbOut = gbb[cur ^ 1];
        ar.fs.stfIn = stf + cur; ar.fs.stfOut = stf + (cur ^ 1);
        ar.fs.qY = qy; ar.fs.c_y = c_y;
        ar.fs.first = (it == 0);
        // sym x
        ar.s[0] = { xh, xsh, tlsFx[cur], qx, bmFx[cur], c_x,
                    fxb[cur], avg ? fxb[cur ^ 1] : ctX,
                    avg ? tlsFx[cur ^ 1] : dummyT,
                    avg ? bmFx[cur ^ 1] : dummyB };
        // sym y
        ar.s[1] = { yh, ysh, tlsFy[cur], qy, bmFy[cur], c_y,
                    fyb[cur], avg ? fyb[cur ^ 1] : ctY,
                    avg ? tlsFy[cur ^ 1] : dummyT,
                    avg ? bmFy[cur ^ 1] : dummyB };
        ct3_kernel<<<grid, 256, 0, stream>>>(ar);
    }

    // final pass was it=10 (cur=0): wrote gp[1], stf[1], ctA/ctX/ctY
    FrArgs fa = { gp[1], stf + 1, qy, a, b, ctA, ctX, ctY, out };
    finredux_kernel<<<256, 256, 0, stream>>>(fa);
}